// Round 1
// baseline (270.463 us; speedup 1.0000x reference)
//
#include <hip/hip_runtime.h>
#include <hip/hip_bf16.h>
#include <stdint.h>

// Problem constants
// B=8, L=4096, T=512, D_H=1280, D_G=768, D_P=256, scale = 1/16

typedef float f32x4 __attribute__((ext_vector_type(4)));
typedef short bf16x8 __attribute__((ext_vector_type(8)));

__device__ __forceinline__ unsigned short f2bf(float f) {
    union { float f; uint32_t u; } v; v.f = f;
    uint32_t u = v.u;
    u += 0x7fffu + ((u >> 16) & 1u);   // RNE
    return (unsigned short)(u >> 16);
}
__device__ __forceinline__ float bf2f(unsigned short h) {
    union { uint32_t u; float f; } v; v.u = ((uint32_t)h) << 16;
    return v.f;
}

// ---------------------------------------------------------------------------
// C[m,n] = scale * sum_k A[m,k] * B[n,k]      (both operands K-major rows)
// A: [M][K] row-major (f32 or bf16), B: [N][K] row-major (f32 or bf16)
// C: [M][N] (bf16 or f32). Tile 128x128, BK=32, 4 waves (2x2), 16x16x32 MFMA.
// ---------------------------------------------------------------------------
template<bool AF32, bool BF32, bool OBF16>
__global__ __launch_bounds__(256)
void gemm_bt(const void* __restrict__ Ap, const void* __restrict__ Bp,
             void* __restrict__ Cp, int M, int N, int K,
             long sA, long sB, long sC, float scale)
{
    constexpr int PK = 40;   // padded LDS row stride (elements): 80B rows, conflict-free b128 reads
    __shared__ __align__(16) unsigned short lA[128 * PK];
    __shared__ __align__(16) unsigned short lB[128 * PK];

    const int mt = M >> 7;
    const int tm = blockIdx.x % mt;
    const int tn = blockIdx.x / mt;
    const int b  = blockIdx.y;
    const int tid = threadIdx.x;
    const int lane = tid & 63, wv = tid >> 6;
    const int wr = wv >> 1, wc = wv & 1;         // wave 2x2 grid, each 64x64
    const int fr = lane & 15, fk = lane >> 4;    // fragment row, k-chunk

    f32x4 acc[4][4] = {};

    const char* Abase = (const char*)Ap;
    const char* Bbase = (const char*)Bp;

    for (int k0 = 0; k0 < K; k0 += 32) {
        // ---- stage A tile (128 x 32) ----
        if constexpr (AF32) {
            const float* A = (const float*)Abase + (long)b * sA + (long)tm * 128 * K + k0;
            #pragma unroll
            for (int it = 0; it < 4; ++it) {
                int chunk = it * 256 + tid;          // 1024 chunks of 4 elems
                int row = chunk >> 3;
                int kc  = (chunk & 7) << 2;
                const float4 v = *(const float4*)(A + (long)row * K + kc);
                ushort4 w;
                w.x = f2bf(v.x); w.y = f2bf(v.y); w.z = f2bf(v.z); w.w = f2bf(v.w);
                *(ushort4*)(&lA[row * PK + kc]) = w;
            }
        } else {
            const unsigned short* A = (const unsigned short*)Abase + (long)b * sA + (long)tm * 128 * K + k0;
            #pragma unroll
            for (int it = 0; it < 2; ++it) {
                int chunk = it * 256 + tid;          // 512 chunks of 8 elems
                int row = chunk >> 2;
                int kc  = (chunk & 3) << 3;
                *(uint4*)(&lA[row * PK + kc]) = *(const uint4*)(A + (long)row * K + kc);
            }
        }
        // ---- stage B tile (128 x 32) ----
        if constexpr (BF32) {
            const float* B = (const float*)Bbase + (long)b * sB + (long)tn * 128 * K + k0;
            #pragma unroll
            for (int it = 0; it < 4; ++it) {
                int chunk = it * 256 + tid;
                int row = chunk >> 3;
                int kc  = (chunk & 7) << 2;
                const float4 v = *(const float4*)(B + (long)row * K + kc);
                ushort4 w;
                w.x = f2bf(v.x); w.y = f2bf(v.y); w.z = f2bf(v.z); w.w = f2bf(v.w);
                *(ushort4*)(&lB[row * PK + kc]) = w;
            }
        } else {
            const unsigned short* B = (const unsigned short*)Bbase + (long)b * sB + (long)tn * 128 * K + k0;
            #pragma unroll
            for (int it = 0; it < 2; ++it) {
                int chunk = it * 256 + tid;
                int row = chunk >> 2;
                int kc  = (chunk & 3) << 3;
                *(uint4*)(&lB[row * PK + kc]) = *(const uint4*)(B + (long)row * K + kc);
            }
        }
        __syncthreads();
        // ---- compute ----
        bf16x8 af[4], bfr[4];
        #pragma unroll
        for (int i = 0; i < 4; ++i)
            af[i] = *(const bf16x8*)(&lA[(wr * 64 + i * 16 + fr) * PK + fk * 8]);
        #pragma unroll
        for (int i = 0; i < 4; ++i)
            bfr[i] = *(const bf16x8*)(&lB[(wc * 64 + i * 16 + fr) * PK + fk * 8]);
        #pragma unroll
        for (int mi = 0; mi < 4; ++mi)
            #pragma unroll
            for (int ni = 0; ni < 4; ++ni)
                acc[mi][ni] = __builtin_amdgcn_mfma_f32_16x16x32_bf16(af[mi], bfr[ni], acc[mi][ni], 0, 0, 0);
        __syncthreads();
    }

    // ---- epilogue: C row = (lane>>4)*4 + j, col = lane&15 (m89-verified) ----
    if constexpr (OBF16) {
        unsigned short* C = (unsigned short*)Cp + (long)b * sC + ((long)tm * 128) * N + (long)tn * 128;
        #pragma unroll
        for (int mi = 0; mi < 4; ++mi)
            #pragma unroll
            for (int ni = 0; ni < 4; ++ni)
                #pragma unroll
                for (int j = 0; j < 4; ++j) {
                    int m = wr * 64 + mi * 16 + fk * 4 + j;
                    int n = wc * 64 + ni * 16 + fr;
                    C[(long)m * N + n] = f2bf(acc[mi][ni][j] * scale);
                }
    } else {
        float* C = (float*)Cp + (long)b * sC + ((long)tm * 128) * N + (long)tn * 128;
        #pragma unroll
        for (int mi = 0; mi < 4; ++mi)
            #pragma unroll
            for (int ni = 0; ni < 4; ++ni)
                #pragma unroll
                for (int j = 0; j < 4; ++j) {
                    int m = wr * 64 + mi * 16 + fk * 4 + j;
                    int n = wc * 64 + ni * 16 + fr;
                    C[(long)m * N + n] = acc[mi][ni][j] * scale;
                }
    }
}

// ---------------------------------------------------------------------------
// C[m,n] = sum_k A[m,k] * B[k,n]   A: bf16 [M][K], B: f32 [K][N], C: f32 [M][N]
// B staged transposed into LDS via per-thread k-strips (coalesced over n).
// ---------------------------------------------------------------------------
__global__ __launch_bounds__(256)
void gemm_kn(const unsigned short* __restrict__ Ap, const float* __restrict__ Bp,
             float* __restrict__ Cp, int M, int N, int K,
             long sA, long sB, long sC)
{
    constexpr int PK = 40;
    __shared__ __align__(16) unsigned short lA[128 * PK];
    __shared__ __align__(16) unsigned short lB[128 * PK];

    const int mt = M >> 7;
    const int tm = blockIdx.x % mt;
    const int tn = blockIdx.x / mt;
    const int b  = blockIdx.y;
    const int tid = threadIdx.x;
    const int lane = tid & 63, wv = tid >> 6;
    const int wr = wv >> 1, wc = wv & 1;
    const int fr = lane & 15, fk = lane >> 4;

    f32x4 acc[4][4] = {};

    const unsigned short* A0 = Ap + (long)b * sA + (long)tm * 128 * K;
    const int nn = tid & 127;        // LDS B row (n within tile)
    const int half = tid >> 7;       // k half: 0 -> k 0..15, 1 -> k 16..31

    for (int k0 = 0; k0 < K; k0 += 32) {
        // ---- stage A (bf16, row-major) ----
        #pragma unroll
        for (int it = 0; it < 2; ++it) {
            int chunk = it * 256 + tid;
            int row = chunk >> 2;
            int kc  = (chunk & 3) << 3;
            *(uint4*)(&lA[row * PK + kc]) = *(const uint4*)(A0 + (long)row * K + k0 + kc);
        }
        // ---- stage B transposed: thread owns column n, k-strip of 16 ----
        {
            const float* Bb = Bp + (long)b * sB + ((long)(k0 + half * 16)) * N + (long)tn * 128 + nn;
            unsigned short t16[16];
            #pragma unroll
            for (int kk = 0; kk < 16; ++kk)
                t16[kk] = f2bf(Bb[(long)kk * N]);
            *(uint4*)(&lB[nn * PK + half * 16 + 0]) = *(uint4*)(&t16[0]);
            *(uint4*)(&lB[nn * PK + half * 16 + 8]) = *(uint4*)(&t16[8]);
        }
        __syncthreads();
        bf16x8 af[4], bfr[4];
        #pragma unroll
        for (int i = 0; i < 4; ++i)
            af[i] = *(const bf16x8*)(&lA[(wr * 64 + i * 16 + fr) * PK + fk * 8]);
        #pragma unroll
        for (int i = 0; i < 4; ++i)
            bfr[i] = *(const bf16x8*)(&lB[(wc * 64 + i * 16 + fr) * PK + fk * 8]);
        #pragma unroll
        for (int mi = 0; mi < 4; ++mi)
            #pragma unroll
            for (int ni = 0; ni < 4; ++ni)
                acc[mi][ni] = __builtin_amdgcn_mfma_f32_16x16x32_bf16(af[mi], bfr[ni], acc[mi][ni], 0, 0, 0);
        __syncthreads();
    }

    float* C = Cp + (long)b * sC + ((long)tm * 128) * N + (long)tn * 128;
    #pragma unroll
    for (int mi = 0; mi < 4; ++mi)
        #pragma unroll
        for (int ni = 0; ni < 4; ++ni)
            #pragma unroll
            for (int j = 0; j < 4; ++j) {
                int m = wr * 64 + mi * 16 + fk * 4 + j;
                int n = wc * 64 + ni * 16 + fr;
                C[(long)m * N + n] = acc[mi][ni][j];
            }
}

// ---------------------------------------------------------------------------
// Row softmax in place on S (bf16), rows of length 4096. One block per row.
// mask[b,l] != 0  ->  logit = -inf (alpha = 0)
// ---------------------------------------------------------------------------
__global__ __launch_bounds__(256)
void softmax_rows(unsigned short* __restrict__ S, const unsigned char* __restrict__ mask)
{
    const int row = blockIdx.x;          // b*512 + t
    const int b = row >> 9;
    const long base = (long)row * 4096;
    const int tid = threadIdx.x, lane = tid & 63, wv = tid >> 6;
    __shared__ float red[8];

    uint4 s0 = *(const uint4*)(S + base + tid * 16);
    uint4 s1 = *(const uint4*)(S + base + tid * 16 + 8);
    uint4 mv = *(const uint4*)(mask + (long)b * 4096 + tid * 16);
    const unsigned char* mb = (const unsigned char*)&mv;

    unsigned int words[8] = { s0.x, s0.y, s0.z, s0.w, s1.x, s1.y, s1.z, s1.w };
    float x[16];
    #pragma unroll
    for (int i = 0; i < 8; ++i) {
        x[2 * i]     = bf2f((unsigned short)(words[i] & 0xffffu));
        x[2 * i + 1] = bf2f((unsigned short)(words[i] >> 16));
    }
    #pragma unroll
    for (int i = 0; i < 16; ++i)
        if (mb[i]) x[i] = -1e30f;

    float m = x[0];
    #pragma unroll
    for (int i = 1; i < 16; ++i) m = fmaxf(m, x[i]);
    #pragma unroll
    for (int off = 32; off; off >>= 1) m = fmaxf(m, __shfl_xor(m, off));
    if (lane == 0) red[wv] = m;
    __syncthreads();
    m = fmaxf(fmaxf(red[0], red[1]), fmaxf(red[2], red[3]));

    float p[16];
    float s = 0.f;
    #pragma unroll
    for (int i = 0; i < 16; ++i) { p[i] = __expf(x[i] - m); s += p[i]; }
    #pragma unroll
    for (int off = 32; off; off >>= 1) s += __shfl_xor(s, off);
    if (lane == 0) red[4 + wv] = s;
    __syncthreads();
    s = (red[4] + red[5]) + (red[6] + red[7]);
    const float inv = 1.0f / s;

    unsigned int ow[8];
    #pragma unroll
    for (int i = 0; i < 8; ++i) {
        unsigned int lo = f2bf(p[2 * i] * inv);
        unsigned int hi = f2bf(p[2 * i + 1] * inv);
        ow[i] = lo | (hi << 16);
    }
    uint4 o0 = { ow[0], ow[1], ow[2], ow[3] };
    uint4 o1 = { ow[4], ow[5], ow[6], ow[7] };
    *(uint4*)(S + base + tid * 16)     = o0;
    *(uint4*)(S + base + tid * 16 + 8) = o1;
}

// ---------------------------------------------------------------------------
extern "C" void kernel_launch(void* const* d_in, const int* in_sizes, int n_in,
                              void* d_out, int out_size, void* d_ws, size_t ws_size,
                              hipStream_t stream)
{
    const float*         H    = (const float*)d_in[0];          // (8,4096,1280)
    const float*         G    = (const float*)d_in[1];          // (8,512,768)
    const unsigned char* mask = (const unsigned char*)d_in[2];  // (8,4096) bool
    const float*         Wk   = (const float*)d_in[3];          // (256,1280)
    const float*         Wq   = (const float*)d_in[4];          // (256,768)
    float*               out  = (float*)d_out;                  // (8,512,1280)

    unsigned short* Kb = (unsigned short*)d_ws;                 // 8*4096*256 bf16
    unsigned short* Qb = Kb + (long)8 * 4096 * 256;             // 8*512*256 bf16
    unsigned short* Sb = Qb + (long)8 * 512 * 256;              // 8*512*4096 bf16

    // 1) K = H @ Wk^T   (M=32768, N=256, K=1280)
    gemm_bt<true, true, true><<<dim3(512, 1), 256, 0, stream>>>(
        H, Wk, Kb, 32768, 256, 1280, 0, 0, 0, 1.0f);
    // 2) Q = G @ Wq^T   (M=4096, N=256, K=768)
    gemm_bt<true, true, true><<<dim3(64, 1), 256, 0, stream>>>(
        G, Wq, Qb, 4096, 256, 768, 0, 0, 0, 1.0f);
    // 3) S = Q @ K^T * scale   per batch: (M=512, N=4096, K=256)
    gemm_bt<false, false, true><<<dim3(128, 8), 256, 0, stream>>>(
        Qb, Kb, Sb, 512, 4096, 256,
        (long)512 * 256, (long)4096 * 256, (long)512 * 4096, 0.0625f);
    // 4) row softmax in place (4096 rows)
    softmax_rows<<<dim3(4096), 256, 0, stream>>>(Sb, mask);
    // 5) Z = alpha @ H   per batch: (M=512, N=1280, K=4096)
    gemm_kn<<<dim3(40, 8), 256, 0, stream>>>(
        Sb, H, out, 512, 1280, 4096,
        (long)512 * 4096, (long)4096 * 1280, (long)512 * 1280);
}

// Round 2
// 243.468 us; speedup vs baseline: 1.1109x; 1.1109x over previous
//
#include <hip/hip_runtime.h>
#include <hip/hip_bf16.h>
#include <stdint.h>

// B=8, L=4096, T=512, D_H=1280, D_G=768, D_P=256, scale = 1/16

typedef float f32x4 __attribute__((ext_vector_type(4)));
typedef short bf16x8 __attribute__((ext_vector_type(8)));

__device__ __forceinline__ unsigned short f2bf(float f) {
    __hip_bfloat16 h = __float2bfloat16(f);   // RNE, hw cvt on gfx950
    return __builtin_bit_cast(unsigned short, h);
}
__device__ __forceinline__ float bf2f(unsigned short h) {
    union { uint32_t u; float f; } v; v.u = ((uint32_t)h) << 16;
    return v.f;
}

// XCD-chunk swizzle (bijective; gridDim.x % 8 == 0 at all call sites)
__device__ __forceinline__ int xcdswz(int bx, int nbx) {
    int cpx = nbx >> 3;
    return (bx & 7) * cpx + (bx >> 3);
}

// LDS addressing: padded stride 40 shorts (80B rows) + XOR swizzle of 8-short
// granules by row bits 3..4. Same formula on write and read -> correct by
// construction; breaks the 8-way write conflicts of the plain layout.
__device__ __forceinline__ int lidx(int row, int kshort) {
    return row * 40 + (((kshort >> 3) ^ ((row >> 3) & 3)) << 3) + (kshort & 7);
}

// ---------------------------------------------------------------------------
// C[m,n] = scale * sum_k A[m,k] * B[n,k]   (both K-major). Tile 128x128,
// BK=32, 4 waves 2x2 (each 64x64), 16x16x32 bf16 MFMA.
// TNF: tn varies fastest in block mapping (use when N-tiles share big A strips)
// ---------------------------------------------------------------------------
template<bool AF32, bool BF32, bool OBF16, bool TNF>
__global__ __launch_bounds__(256)
void gemm_bt(const void* __restrict__ Ap, const void* __restrict__ Bp,
             void* __restrict__ Cp, int M, int N, int K,
             long sA, long sB, long sC, float scale)
{
    __shared__ __align__(16) unsigned short lA[128 * 40];
    __shared__ __align__(16) unsigned short lB[128 * 40];

    const int bx = xcdswz(blockIdx.x, gridDim.x);
    const int mt = M >> 7, nt = N >> 7;
    const int tm = TNF ? (bx / nt) : (bx % mt);
    const int tn = TNF ? (bx % nt) : (bx / mt);
    const int b  = blockIdx.y;
    const int tid = threadIdx.x;
    const int lane = tid & 63, wv = tid >> 6;
    const int wr = wv >> 1, wc = wv & 1;
    const int fr = lane & 15, fk = lane >> 4;

    f32x4 acc[4][4] = {};

    const char* Abase = (const char*)Ap;
    const char* Bbase = (const char*)Bp;

    for (int k0 = 0; k0 < K; k0 += 32) {
        if constexpr (AF32) {
            const float* A = (const float*)Abase + (long)b * sA + (long)tm * 128 * K + k0;
            #pragma unroll
            for (int it = 0; it < 4; ++it) {
                int chunk = it * 256 + tid;
                int row = chunk >> 3;
                int kc  = (chunk & 7) << 2;
                const float4 v = *(const float4*)(A + (long)row * K + kc);
                ushort4 w;
                w.x = f2bf(v.x); w.y = f2bf(v.y); w.z = f2bf(v.z); w.w = f2bf(v.w);
                *(ushort4*)(&lA[lidx(row, kc)]) = w;
            }
        } else {
            const unsigned short* A = (const unsigned short*)Abase + (long)b * sA + (long)tm * 128 * K + k0;
            #pragma unroll
            for (int it = 0; it < 2; ++it) {
                int chunk = it * 256 + tid;
                int row = chunk >> 2;
                int kc  = (chunk & 3) << 3;
                *(uint4*)(&lA[lidx(row, kc)]) = *(const uint4*)(A + (long)row * K + kc);
            }
        }
        if constexpr (BF32) {
            const float* B = (const float*)Bbase + (long)b * sB + (long)tn * 128 * K + k0;
            #pragma unroll
            for (int it = 0; it < 4; ++it) {
                int chunk = it * 256 + tid;
                int row = chunk >> 3;
                int kc  = (chunk & 7) << 2;
                const float4 v = *(const float4*)(B + (long)row * K + kc);
                ushort4 w;
                w.x = f2bf(v.x); w.y = f2bf(v.y); w.z = f2bf(v.z); w.w = f2bf(v.w);
                *(ushort4*)(&lB[lidx(row, kc)]) = w;
            }
        } else {
            const unsigned short* B = (const unsigned short*)Bbase + (long)b * sB + (long)tn * 128 * K + k0;
            #pragma unroll
            for (int it = 0; it < 2; ++it) {
                int chunk = it * 256 + tid;
                int row = chunk >> 2;
                int kc  = (chunk & 3) << 3;
                *(uint4*)(&lB[lidx(row, kc)]) = *(const uint4*)(B + (long)row * K + kc);
            }
        }
        __syncthreads();
        bf16x8 af[4], bfr[4];
        #pragma unroll
        for (int i = 0; i < 4; ++i)
            af[i] = *(const bf16x8*)(&lA[lidx(wr * 64 + i * 16 + fr, fk * 8)]);
        #pragma unroll
        for (int i = 0; i < 4; ++i)
            bfr[i] = *(const bf16x8*)(&lB[lidx(wc * 64 + i * 16 + fr, fk * 8)]);
        #pragma unroll
        for (int mi = 0; mi < 4; ++mi)
            #pragma unroll
            for (int ni = 0; ni < 4; ++ni)
                acc[mi][ni] = __builtin_amdgcn_mfma_f32_16x16x32_bf16(af[mi], bfr[ni], acc[mi][ni], 0, 0, 0);
        __syncthreads();
    }

    if constexpr (OBF16) {
        unsigned short* C = (unsigned short*)Cp + (long)b * sC + ((long)tm * 128) * N + (long)tn * 128;
        #pragma unroll
        for (int mi = 0; mi < 4; ++mi)
            #pragma unroll
            for (int ni = 0; ni < 4; ++ni)
                #pragma unroll
                for (int j = 0; j < 4; ++j) {
                    int m = wr * 64 + mi * 16 + fk * 4 + j;
                    int n = wc * 64 + ni * 16 + fr;
                    C[(long)m * N + n] = f2bf(acc[mi][ni][j] * scale);
                }
    } else {
        float* C = (float*)Cp + (long)b * sC + ((long)tm * 128) * N + (long)tn * 128;
        #pragma unroll
        for (int mi = 0; mi < 4; ++mi)
            #pragma unroll
            for (int ni = 0; ni < 4; ++ni)
                #pragma unroll
                for (int j = 0; j < 4; ++j) {
                    int m = wr * 64 + mi * 16 + fk * 4 + j;
                    int n = wc * 64 + ni * 16 + fr;
                    C[(long)m * N + n] = acc[mi][ni][j] * scale;
                }
    }
}

// ---------------------------------------------------------------------------
// C[m,n] = sum_k A[m,k]*B[k,n]. A: bf16 [M][K], B: f32 [K][N], C: f32.
// Tile 128(M) x 64(N), BK=32, 4 waves 2x2 (each 64x32). Grid 640 blocks.
// ---------------------------------------------------------------------------
__global__ __launch_bounds__(256)
void gemm_kn(const unsigned short* __restrict__ Ap, const float* __restrict__ Bp,
             float* __restrict__ Cp, int M, int N, int K,
             long sA, long sB, long sC)
{
    __shared__ __align__(16) unsigned short lA[128 * 40];
    __shared__ __align__(16) unsigned short lB[64 * 40];

    const int bx = xcdswz(blockIdx.x, gridDim.x);
    const int mt = M >> 7;                 // 4
    const int tm = bx % mt;
    const int tn = bx / mt;                // 0..19
    const int b  = blockIdx.y;
    const int tid = threadIdx.x;
    const int lane = tid & 63, wv = tid >> 6;
    const int wr = wv >> 1, wc = wv & 1;   // wave tile 64x32
    const int fr = lane & 15, fk = lane >> 4;

    f32x4 acc[4][2] = {};

    const unsigned short* A0 = Ap + (long)b * sA + (long)tm * 128 * K;
    const int nn    = tid & 63;            // B column within tile
    const int khalf = tid >> 6;            // 0..3 -> k-subtile of 8

    for (int k0 = 0; k0 < K; k0 += 32) {
        // A: 128x32 bf16 row-major, 2 uint4 per thread
        #pragma unroll
        for (int it = 0; it < 2; ++it) {
            int chunk = it * 256 + tid;
            int row = chunk >> 2;
            int kc  = (chunk & 3) << 3;
            *(uint4*)(&lA[lidx(row, kc)]) = *(const uint4*)(A0 + (long)row * K + k0 + kc);
        }
        // B transposed: thread owns column nn, k-strip of 8 (stride-N loads)
        {
            const float* Bb = Bp + (long)b * sB + (long)(k0 + khalf * 8) * N + (long)tn * 64 + nn;
            unsigned short t8[8];
            #pragma unroll
            for (int kk = 0; kk < 8; ++kk)
                t8[kk] = f2bf(Bb[(long)kk * N]);
            *(uint4*)(&lB[lidx(nn, khalf * 8)]) = *(uint4*)(&t8[0]);
        }
        __syncthreads();
        bf16x8 af[4], bfr[2];
        #pragma unroll
        for (int i = 0; i < 4; ++i)
            af[i] = *(const bf16x8*)(&lA[lidx(wr * 64 + i * 16 + fr, fk * 8)]);
        #pragma unroll
        for (int i = 0; i < 2; ++i)
            bfr[i] = *(const bf16x8*)(&lB[lidx(wc * 32 + i * 16 + fr, fk * 8)]);
        #pragma unroll
        for (int mi = 0; mi < 4; ++mi)
            #pragma unroll
            for (int ni = 0; ni < 2; ++ni)
                acc[mi][ni] = __builtin_amdgcn_mfma_f32_16x16x32_bf16(af[mi], bfr[ni], acc[mi][ni], 0, 0, 0);
        __syncthreads();
    }

    float* C = Cp + (long)b * sC + ((long)tm * 128) * N + (long)tn * 64;
    #pragma unroll
    for (int mi = 0; mi < 4; ++mi)
        #pragma unroll
        for (int ni = 0; ni < 2; ++ni)
            #pragma unroll
            for (int j = 0; j < 4; ++j) {
                int m = wr * 64 + mi * 16 + fk * 4 + j;
                int n = wc * 32 + ni * 16 + fr;
                C[(long)m * N + n] = acc[mi][ni][j];
            }
}

// ---------------------------------------------------------------------------
// Row softmax in place on S (bf16), rows of length 4096. One block per row.
// ---------------------------------------------------------------------------
__global__ __launch_bounds__(256)
void softmax_rows(unsigned short* __restrict__ S, const unsigned char* __restrict__ mask)
{
    const int row = blockIdx.x;
    const int b = row >> 9;
    const long base = (long)row * 4096;
    const int tid = threadIdx.x, lane = tid & 63, wv = tid >> 6;
    __shared__ float red[8];

    uint4 s0 = *(const uint4*)(S + base + tid * 16);
    uint4 s1 = *(const uint4*)(S + base + tid * 16 + 8);
    uint4 mv = *(const uint4*)(mask + (long)b * 4096 + tid * 16);
    const unsigned char* mb = (const unsigned char*)&mv;

    unsigned int words[8] = { s0.x, s0.y, s0.z, s0.w, s1.x, s1.y, s1.z, s1.w };
    float x[16];
    #pragma unroll
    for (int i = 0; i < 8; ++i) {
        x[2 * i]     = bf2f((unsigned short)(words[i] & 0xffffu));
        x[2 * i + 1] = bf2f((unsigned short)(words[i] >> 16));
    }
    #pragma unroll
    for (int i = 0; i < 16; ++i)
        if (mb[i]) x[i] = -1e30f;

    float m = x[0];
    #pragma unroll
    for (int i = 1; i < 16; ++i) m = fmaxf(m, x[i]);
    #pragma unroll
    for (int off = 32; off; off >>= 1) m = fmaxf(m, __shfl_xor(m, off));
    if (lane == 0) red[wv] = m;
    __syncthreads();
    m = fmaxf(fmaxf(red[0], red[1]), fmaxf(red[2], red[3]));

    float p[16];
    float s = 0.f;
    #pragma unroll
    for (int i = 0; i < 16; ++i) { p[i] = __expf(x[i] - m); s += p[i]; }
    #pragma unroll
    for (int off = 32; off; off >>= 1) s += __shfl_xor(s, off);
    if (lane == 0) red[4 + wv] = s;
    __syncthreads();
    s = (red[4] + red[5]) + (red[6] + red[7]);
    const float inv = 1.0f / s;

    unsigned int ow[8];
    #pragma unroll
    for (int i = 0; i < 8; ++i) {
        unsigned int lo = f2bf(p[2 * i] * inv);
        unsigned int hi = f2bf(p[2 * i + 1] * inv);
        ow[i] = lo | (hi << 16);
    }
    uint4 o0 = { ow[0], ow[1], ow[2], ow[3] };
    uint4 o1 = { ow[4], ow[5], ow[6], ow[7] };
    *(uint4*)(S + base + tid * 16)     = o0;
    *(uint4*)(S + base + tid * 16 + 8) = o1;
}

// ---------------------------------------------------------------------------
extern "C" void kernel_launch(void* const* d_in, const int* in_sizes, int n_in,
                              void* d_out, int out_size, void* d_ws, size_t ws_size,
                              hipStream_t stream)
{
    const float*         H    = (const float*)d_in[0];
    const float*         G    = (const float*)d_in[1];
    const unsigned char* mask = (const unsigned char*)d_in[2];
    const float*         Wk   = (const float*)d_in[3];
    const float*         Wq   = (const float*)d_in[4];
    float*               out  = (float*)d_out;

    unsigned short* Kb = (unsigned short*)d_ws;
    unsigned short* Qb = Kb + (long)8 * 4096 * 256;
    unsigned short* Sb = Qb + (long)8 * 512 * 256;

    // 1) K = H @ Wk^T  (M=32768,N=256,K=1280). TNF: the 2 tn-sharers of each
    //    H strip are adjacent + co-XCD -> H fetched ~once.
    gemm_bt<true, true, true, true><<<dim3(512, 1), 256, 0, stream>>>(
        H, Wk, Kb, 32768, 256, 1280, 0, 0, 0, 1.0f);
    // 2) Q = G @ Wq^T  (M=4096,N=256,K=768)
    gemm_bt<true, true, true, true><<<dim3(64, 1), 256, 0, stream>>>(
        G, Wq, Qb, 4096, 256, 768, 0, 0, 0, 1.0f);
    // 3) S = Q @ K^T * scale  per batch (M=512,N=4096,K=256)
    gemm_bt<false, false, true, false><<<dim3(128, 8), 256, 0, stream>>>(
        Qb, Kb, Sb, 512, 4096, 256,
        (long)512 * 256, (long)4096 * 256, (long)512 * 4096, 0.0625f);
    // 4) row softmax in place
    softmax_rows<<<dim3(4096), 256, 0, stream>>>(Sb, mask);
    // 5) Z = alpha @ H  per batch (M=512,N=1280,K=4096), 128x64 tiles -> 640 blocks
    gemm_kn<<<dim3(80, 8), 256, 0, stream>>>(
        Sb, H, out, 512, 1280, 4096,
        (long)512 * 4096, (long)4096 * 1280, (long)512 * 1280);
}